// Round 5
// baseline (1175.030 us; speedup 1.0000x reference)
//
#include <hip/hip_runtime.h>
#include <hip/hip_bf16.h>

#define NB 8192   // batch
#define ND 1024   // feature dim

typedef __bf16 bf16x8 __attribute__((ext_vector_type(8)));
typedef float  f32x4  __attribute__((ext_vector_type(4)));

// async global -> LDS, 16B per lane. LDS dest = wave-uniform base + lane*16.
__device__ inline void gload_lds16(const void* g, void* l) {
    __builtin_amdgcn_global_load_lds(
        (const __attribute__((address_space(1))) unsigned int*)g,
        (__attribute__((address_space(3))) unsigned int*)l,
        16, 0, 0);
}

__device__ inline unsigned short f2bf(float x) {
    unsigned int u = __float_as_uint(x);
    return (unsigned short)((u + 0x7fffu + ((u >> 16) & 1u)) >> 16);
}

#define BARRIER() asm volatile("s_barrier" ::: "memory")
#define VMCNT0()  asm volatile("s_waitcnt vmcnt(0)" ::: "memory")

// ---------------------------------------------------------------------------
// Kernel 1: per-row L2 norms of A and B + bf16 conversion into workspace.
// ---------------------------------------------------------------------------
__global__ __launch_bounds__(256) void prep_kernel(
    const float* __restrict__ A, const float* __restrict__ Bm,
    unsigned short* __restrict__ wa, unsigned short* __restrict__ wb,
    float* __restrict__ na, float* __restrict__ nb)
{
    int b = blockIdx.x;
    int wid = threadIdx.x >> 6, lane = threadIdx.x & 63;
    const float* src; unsigned short* dst; float* nrm; int row;
    if (b < 2048) { src = A;  dst = wa; nrm = na; row = b * 4 + wid; }
    else          { src = Bm; dst = wb; nrm = nb; row = (b - 2048) * 4 + wid; }

    const float*    rp = src + (size_t)row * ND;
    unsigned short* wp = dst + (size_t)row * ND;

    float ss = 0.f;
#pragma unroll
    for (int t = 0; t < 4; ++t) {
        int c = lane * 4 + t * 256;
        float4 v = *reinterpret_cast<const float4*>(rp + c);
        ss += v.x * v.x + v.y * v.y + v.z * v.z + v.w * v.w;
        ushort4 u;
        u.x = f2bf(v.x); u.y = f2bf(v.y); u.z = f2bf(v.z); u.w = f2bf(v.w);
        *reinterpret_cast<ushort4*>(wp + c) = u;
    }
#pragma unroll
    for (int off = 32; off; off >>= 1) ss += __shfl_xor(ss, off);
    if (lane == 0) nrm[row] = sqrtf(ss);
}

// ---------------------------------------------------------------------------
// Kernel 2: label histogram (integer LDS atomics -> deterministic).
// ---------------------------------------------------------------------------
__global__ __launch_bounds__(256) void hist_kernel(
    const int* __restrict__ labels, int* __restrict__ hist)
{
    __shared__ int h[128];
    int tid = threadIdx.x;
    if (tid < 128) h[tid] = 0;
    __syncthreads();
    for (int i = tid; i < NB; i += 256) atomicAdd(&h[labels[i]], 1);
    __syncthreads();
    if (tid < 128) hist[tid] = h[tid];
}

// ---------------------------------------------------------------------------
// Kernel 3: 256x256-tile bf16 GEMM, BK=32, 2 LDS buffers (64 KiB total) so
// TWO blocks co-reside per CU (16 waves) — inter-block overlap (m114) hides
// barrier drains, staging latency, and the store epilogue of the other block.
// Per K-tile: stage t+1 (4 gloads) -> 12 ds_read_b128 -> 32 MFMA ->
// vmcnt(0) -> s_barrier. T2 granule swizzle (g ^ (row>>1)&3) on both sides.
// Epilogue: scale to cos, nontemporal-write C, fused per-row loss partials.
// ---------------------------------------------------------------------------
__global__ __launch_bounds__(512, 4) void gemm_cos(
    const unsigned short* __restrict__ wa, const unsigned short* __restrict__ wb,
    const float* __restrict__ na, const float* __restrict__ nb,
    const int* __restrict__ labels,
    float* __restrict__ C, float* __restrict__ pe, float* __restrict__ pm)
{
    // [buf 2][A/B 2][half 2][128 rows x 32 cols] bf16 = 32768 shorts = 64 KiB
    __shared__ unsigned short lds[32768];

    const int bid = blockIdx.x;                 // 1024 blocks
    const int tm  = (bid & 7) * 4 + ((bid >> 3) & 3);
    const int tn  = bid >> 5;

    const int tid  = threadIdx.x;
    const int lane = tid & 63;
    const int wid  = tid >> 6;
    const int wr   = wid >> 2, wc = wid & 3;
    const int l15  = lane & 15, lg = lane >> 4;

    const int m0 = tm * 256, n0 = tn * 256;

    // Staging: thread tid -> row tid>>2 (0..127 per half), granule tid&3;
    // global granule pre-swizzled so LDS[r][g] holds global g^((r>>1)&3).
    const int srow = tid >> 2;
    const int sg   = (tid & 3) ^ ((tid >> 3) & 3);
    const unsigned short* pA0 = wa + (size_t)(m0 + srow) * ND + sg * 8;
    const unsigned short* pA1 = pA0 + 128 * ND;
    const unsigned short* pB0 = wb + (size_t)(n0 + srow) * ND + sg * 8;
    const unsigned short* pB1 = pB0 + 128 * ND;
    const int stW = wid * 512;   // wave-uniform dest base (shorts) in a half

    // Fragment reads: granule swizzle kg = (lg ^ ((row>>1)&3))*8, row%16=l15.
    const int kg  = ((lg ^ ((lane >> 1) & 3)) * 8);
    const int rdA = wr * 4096 + l15 * 32 + kg;                              // + q*2048 + m*512
    const int rdB = 8192 + (wc >> 1) * 4096 + ((wc & 1) * 64 + l15) * 32 + kg;  // + n*512

    f32x4 acc[8][4];
#pragma unroll
    for (int i = 0; i < 8; ++i)
#pragma unroll
        for (int j = 0; j < 4; ++j) acc[i][j] = (f32x4){0.f, 0.f, 0.f, 0.f};

#define STAGE_TILE(t, BUFO) do { \
    gload_lds16(pA0 + (t) * 32, &lds[(BUFO) + stW]); \
    gload_lds16(pA1 + (t) * 32, &lds[(BUFO) + 4096 + stW]); \
    gload_lds16(pB0 + (t) * 32, &lds[(BUFO) + 8192 + stW]); \
    gload_lds16(pB1 + (t) * 32, &lds[(BUFO) + 12288 + stW]); } while (0)

#define COMPUTE(BUFO) do { \
    bf16x8 bq[4], af[4]; \
    _Pragma("unroll") \
    for (int n_ = 0; n_ < 4; ++n_) \
        bq[n_] = *reinterpret_cast<const bf16x8*>(&lds[(BUFO) + rdB + n_ * 512]); \
    _Pragma("unroll") \
    for (int m_ = 0; m_ < 4; ++m_) \
        af[m_] = *reinterpret_cast<const bf16x8*>(&lds[(BUFO) + rdA + m_ * 512]); \
    _Pragma("unroll") \
    for (int m_ = 0; m_ < 4; ++m_) \
        _Pragma("unroll") \
        for (int n_ = 0; n_ < 4; ++n_) \
            acc[m_][n_] = __builtin_amdgcn_mfma_f32_16x16x32_bf16( \
                af[m_], bq[n_], acc[m_][n_], 0, 0, 0); \
    _Pragma("unroll") \
    for (int m_ = 0; m_ < 4; ++m_) \
        af[m_] = *reinterpret_cast<const bf16x8*>(&lds[(BUFO) + rdA + 2048 + m_ * 512]); \
    _Pragma("unroll") \
    for (int m_ = 0; m_ < 4; ++m_) \
        _Pragma("unroll") \
        for (int n_ = 0; n_ < 4; ++n_) \
            acc[4 + m_][n_] = __builtin_amdgcn_mfma_f32_16x16x32_bf16( \
                af[m_], bq[n_], acc[4 + m_][n_], 0, 0, 0); \
    } while (0)

    // Prologue: stage tile 0 into buf0.
    STAGE_TILE(0, 0);
    VMCNT0();
    BARRIER();

#pragma unroll
    for (int tp = 0; tp < 16; ++tp) {
        // even tile 2tp from buf0; stage 2tp+1 -> buf1
        if (2 * tp + 1 < 32) STAGE_TILE(2 * tp + 1, 16384);
        COMPUTE(0);
        VMCNT0();
        BARRIER();
        // odd tile 2tp+1 from buf1; stage 2tp+2 -> buf0
        if (2 * tp + 2 < 32) STAGE_TILE(2 * tp + 2, 0);
        COMPUTE(16384);
        VMCNT0();
        BARRIER();
    }

#undef COMPUTE
#undef STAGE_TILE

    // ---------------- epilogue: cos write + fused loss partials ------------
    __syncthreads();                 // LDS buffers now reusable
    float* pl = reinterpret_cast<float*>(lds);   // [256 rows][4 wc][2] floats

    float nbv[4]; int labc[4];
#pragma unroll
    for (int n = 0; n < 4; ++n) {
        int c = n0 + wc * 64 + n * 16 + l15;
        nbv[n] = nb[c]; labc[n] = labels[c];
    }

#pragma unroll
    for (int m = 0; m < 8; ++m) {
#pragma unroll
        for (int jj = 0; jj < 4; ++jj) {
            int rl = wr * 128 + m * 16 + lg * 4 + jj;   // 0..255
            int r  = m0 + rl;
            float nav = na[r]; int labr = labels[r];
            float es = 0.f, ms = 0.f;
#pragma unroll
            for (int n = 0; n < 4; ++n) {
                int c = n0 + wc * 64 + n * 16 + l15;
                float v = acc[m][n][jj] / fmaxf(nav * nbv[n], 1e-8f);
                __builtin_nontemporal_store(v, &C[(size_t)r * NB + c]);
                es += __expf(v);
                ms += (labc[n] == labr) ? v : 0.f;
            }
#pragma unroll
            for (int off = 1; off < 16; off <<= 1) {
                es += __shfl_xor(es, off);
                ms += __shfl_xor(ms, off);
            }
            if (l15 == 0) {
                int o = (rl * 4 + wc) * 2;
                pl[o] = es; pl[o + 1] = ms;
            }
        }
    }
    __syncthreads();
    if (tid < 256) {
        float es = 0.f, ms = 0.f;
#pragma unroll
        for (int w = 0; w < 4; ++w) {
            es += pl[(tid * 4 + w) * 2];
            ms += pl[(tid * 4 + w) * 2 + 1];
        }
        int grow = m0 + tid;
        pe[tn * NB + grow] = es;
        pm[tn * NB + grow] = ms;
    }
}

// ---------------------------------------------------------------------------
// Kernel 4: reduce column-tile partials -> per-row loss.
// ---------------------------------------------------------------------------
__global__ __launch_bounds__(256) void loss_final(
    const float* __restrict__ pe, const float* __restrict__ pm,
    const int* __restrict__ labels, const int* __restrict__ hist,
    float* __restrict__ per_row)
{
    int row = blockIdx.x * 256 + threadIdx.x;
    float es = 0.f, ms = 0.f;
#pragma unroll
    for (int t = 0; t < 32; ++t) {
        es += pe[t * NB + row];
        ms += pm[t * NB + row];
    }
    per_row[row] = logf(es) - ms / (float)hist[labels[row]];
}

// ---------------------------------------------------------------------------
// Kernel 5: deterministic mean of per_row -> out[0]
// ---------------------------------------------------------------------------
__global__ __launch_bounds__(256) void finalize(
    const float* __restrict__ per_row, float* __restrict__ out)
{
    __shared__ float sm[256];
    float s = 0.f;
    for (int i = threadIdx.x; i < NB; i += 256) s += per_row[i];
    sm[threadIdx.x] = s;
    __syncthreads();
    for (int k = 128; k; k >>= 1) {
        if (threadIdx.x < k) sm[threadIdx.x] += sm[threadIdx.x + k];
        __syncthreads();
    }
    if (threadIdx.x == 0) out[0] = sm[0] * (1.0f / (float)NB);
}

extern "C" void kernel_launch(void* const* d_in, const int* in_sizes, int n_in,
                              void* d_out, int out_size, void* d_ws, size_t ws_size,
                              hipStream_t stream) {
    const int*   labels = (const int*)d_in[0];
    const float* A      = (const float*)d_in[1];
    const float* Bm     = (const float*)d_in[2];
    float* out = (float*)d_out;

    // workspace layout (~36.2 MB)
    char* ws = (char*)d_ws;
    unsigned short* wa = (unsigned short*)(ws);                     // 16 MB
    unsigned short* wb = (unsigned short*)(ws + 16777216);          // 16 MB
    float* na      = (float*)(ws + 33554432);                       // 32 KB
    float* nb      = (float*)(ws + 33554432 + 32768);               // 32 KB
    float* per_row = (float*)(ws + 33554432 + 65536);               // 32 KB
    int*   hist    = (int*)  (ws + 33554432 + 98304);               // 512 B
    float* pe      = (float*)(ws + 33554432 + 131072);              // 1 MB
    float* pm      = (float*)(ws + 33554432 + 131072 + 1048576);    // 1 MB

    float* cosm = out + 1;   // out[0]=loss, out[1..] = cos_score row-major

    prep_kernel<<<4096, 256, 0, stream>>>(A, Bm, wa, wb, na, nb);
    hist_kernel<<<1,    256, 0, stream>>>(labels, hist);
    gemm_cos   <<<1024, 512, 0, stream>>>(wa, wb, na, nb, labels, cosm, pe, pm);
    loss_final <<<32,   256, 0, stream>>>(pe, pm, labels, hist, per_row);
    finalize   <<<1,    256, 0, stream>>>(per_row, out);
}

// Round 6
// 278.884 us; speedup vs baseline: 4.2133x; 4.2133x over previous
//
#include <hip/hip_runtime.h>
#include <hip/hip_bf16.h>

#define NB 8192   // batch
#define ND 1024   // feature dim

typedef int   i32x4 __attribute__((ext_vector_type(4)));
typedef int   i32x8 __attribute__((ext_vector_type(8)));
typedef float f32x4 __attribute__((ext_vector_type(4)));

// async global -> LDS, 16B per lane. LDS dest = wave-uniform base + lane*16.
__device__ inline void gload_lds16(const void* g, void* l) {
    __builtin_amdgcn_global_load_lds(
        (const __attribute__((address_space(1))) unsigned int*)g,
        (__attribute__((address_space(3))) unsigned int*)l,
        16, 0, 0);
}

#define BARRIER() asm volatile("s_barrier" ::: "memory")
#define VMCNT0()  asm volatile("s_waitcnt vmcnt(0)" ::: "memory")
#define VMCNT8()  asm volatile("s_waitcnt vmcnt(8)" ::: "memory")

// ---------------------------------------------------------------------------
// Kernel 1: per-row L2 norms (f32) of A and B + fp8-e4m3 conversion into ws.
// One wave per row; 4096 blocks x 256 threads.
// ---------------------------------------------------------------------------
__global__ __launch_bounds__(256) void prep_kernel(
    const float* __restrict__ A, const float* __restrict__ Bm,
    unsigned char* __restrict__ wa, unsigned char* __restrict__ wb,
    float* __restrict__ na, float* __restrict__ nb)
{
    int b = blockIdx.x;
    int wid = threadIdx.x >> 6, lane = threadIdx.x & 63;
    const float* src; unsigned char* dst; float* nrm; int row;
    if (b < 2048) { src = A;  dst = wa; nrm = na; row = b * 4 + wid; }
    else          { src = Bm; dst = wb; nrm = nb; row = (b - 2048) * 4 + wid; }

    const float*   rp = src + (size_t)row * ND;
    unsigned char* wp = dst + (size_t)row * ND;

    float ss = 0.f;
#pragma unroll
    for (int t = 0; t < 4; ++t) {
        int c = lane * 4 + t * 256;
        float4 v = *reinterpret_cast<const float4*>(rp + c);
        ss += v.x * v.x + v.y * v.y + v.z * v.z + v.w * v.w;
        int u = __builtin_amdgcn_cvt_pk_fp8_f32(v.x, v.y, 0, false);
        u     = __builtin_amdgcn_cvt_pk_fp8_f32(v.z, v.w, u, true);
        *reinterpret_cast<unsigned int*>(wp + c) = (unsigned int)u;
    }
#pragma unroll
    for (int off = 32; off; off >>= 1) ss += __shfl_xor(ss, off);
    if (lane == 0) nrm[row] = sqrtf(ss);
}

// ---------------------------------------------------------------------------
// Kernel 2: label histogram (integer LDS atomics -> deterministic).
// ---------------------------------------------------------------------------
__global__ __launch_bounds__(256) void hist_kernel(
    const int* __restrict__ labels, int* __restrict__ hist)
{
    __shared__ int h[128];
    int tid = threadIdx.x;
    if (tid < 128) h[tid] = 0;
    __syncthreads();
    for (int i = tid; i < NB; i += 256) atomicAdd(&h[labels[i]], 1);
    __syncthreads();
    if (tid < 128) hist[tid] = h[tid];
}

// ---------------------------------------------------------------------------
// Kernel 3: 128x128-tile MX-fp8 GEMM (m97 structure + m148 dtype port).
// 4 waves (2x2), each wave 64x64 via 4x4 of mfma_scale 16x16x128 (scales=1.0).
// BK=128 bytes; K-loop = 8. LDS: 2 bufs x (A 16K + B 16K) = 64 KiB ->
// ~2 blocks/CU co-resident (m114 overlap hides staging + epilogue).
// Counted wait: stage(t+1) then vmcnt(8) = wait only tile t (issued a full
// iteration earlier -> ~0 stall). T2 granule swizzle g ^= (row&7) on both
// the pre-swizzled global source and the ds_read address.
// Epilogue: scale to cos, nontemporal-write C, fused per-row loss partials.
// ---------------------------------------------------------------------------
__global__ __launch_bounds__(256) void gemm_cos(
    const unsigned char* __restrict__ wa, const unsigned char* __restrict__ wb,
    const float* __restrict__ na, const float* __restrict__ nb,
    const int* __restrict__ labels,
    float* __restrict__ C, float* __restrict__ pe, float* __restrict__ pm)
{
    __shared__ __align__(16) unsigned char lds8[65536];  // [buf2][A 16K|B 16K]

    const int bid = blockIdx.x;                  // 4096 blocks
    const int swz = (bid & 7) * 512 + (bid >> 3);   // XCD-contiguous, bijective
    const int tm  = swz >> 6, tn = swz & 63;        // per XCD: 8 tm-rows, tn streams

    const int tid  = threadIdx.x;
    const int lane = tid & 63;
    const int wid  = tid >> 6;
    const int wr   = wid >> 1, wc = wid & 1;
    const int l15  = lane & 15, lg = lane >> 4;

    const int m0 = tm * 128, n0 = tn * 128;

    // Staging: thread -> row tid>>3 (0..31 per issue), 16B granule tid&7;
    // global granule pre-swizzled: (tid&7) ^ (row&7), so LDS[r][g] holds
    // global granule g ^ (r&7).
    const int srow = tid >> 3;
    const int sgr  = (tid & 7) ^ (srow & 7);
    const unsigned char* pA = wa + (size_t)(m0 + srow) * ND + sgr * 16;
    const unsigned char* pB = wb + (size_t)(n0 + srow) * ND + sgr * 16;
    const int stW = wid * 1024;      // wave-uniform LDS dest base per issue

    // Fragment reads: global granules {2lg, 2lg+1} -> LDS granule ^ (row&7).
    const int gsw  = (((2 * lg) ^ (l15 & 7)) * 16);
    const int aoff = (wr * 64 + l15) * 128 + gsw;            // + m*2048
    const int boff = 16384 + (wc * 64 + l15) * 128 + gsw;    // + n*2048

    f32x4 acc[4][4];
#pragma unroll
    for (int i = 0; i < 4; ++i)
#pragma unroll
        for (int j = 0; j < 4; ++j) acc[i][j] = (f32x4){0.f, 0.f, 0.f, 0.f};

#define STAGE(kt, BUF) do { \
    _Pragma("unroll") \
    for (int i_ = 0; i_ < 4; ++i_) { \
        gload_lds16(pA + (size_t)i_ * 32 * ND + (kt) * 128, \
                    &lds8[(BUF) + i_ * 4096 + stW]); \
        gload_lds16(pB + (size_t)i_ * 32 * ND + (kt) * 128, \
                    &lds8[(BUF) + 16384 + i_ * 4096 + stW]); \
    } } while (0)

// read 32 B (one K-block of 32 fp8) as v8i32; low 16 B at off, high at off^16
#define RD32(off) __builtin_shufflevector( \
    *reinterpret_cast<const i32x4*>(&lds8[(off)]), \
    *reinterpret_cast<const i32x4*>(&lds8[(off) ^ 16]), 0, 1, 2, 3, 4, 5, 6, 7)

    STAGE(0, 0);
#pragma unroll
    for (int kt = 0; kt < 8; ++kt) {
        const int cb = (kt & 1) * 32768;
        if (kt < 7) { STAGE(kt + 1, cb ^ 32768); VMCNT8(); }
        else        { VMCNT0(); }
        BARRIER();
        i32x8 bq[4];
#pragma unroll
        for (int n = 0; n < 4; ++n) bq[n] = RD32(cb + boff + n * 2048);
#pragma unroll
        for (int m = 0; m < 4; ++m) {
            i32x8 am = RD32(cb + aoff + m * 2048);
#pragma unroll
            for (int n = 0; n < 4; ++n)
                acc[m][n] = __builtin_amdgcn_mfma_scale_f32_16x16x128_f8f6f4(
                    am, bq[n], acc[m][n], 0, 0, 0, 127, 0, 127);
        }
        BARRIER();
    }

#undef RD32
#undef STAGE

    // ---------------- epilogue: cos write + fused loss partials ------------
    __syncthreads();                 // LDS reusable
    float* pl = reinterpret_cast<float*>(lds8);   // [128 rows][2 wc][2] floats

    float nbv[4]; int labc[4];
#pragma unroll
    for (int n = 0; n < 4; ++n) {
        int c = n0 + wc * 64 + n * 16 + l15;
        nbv[n] = nb[c]; labc[n] = labels[c];
    }

#pragma unroll
    for (int m = 0; m < 4; ++m) {
#pragma unroll
        for (int jj = 0; jj < 4; ++jj) {
            int rl = wr * 64 + m * 16 + lg * 4 + jj;   // 0..127
            int r  = m0 + rl;
            float nav = na[r]; int labr = labels[r];
            float es = 0.f, ms = 0.f;
#pragma unroll
            for (int n = 0; n < 4; ++n) {
                int c = n0 + wc * 64 + n * 16 + l15;
                float v = acc[m][n][jj] / fmaxf(nav * nbv[n], 1e-8f);
                __builtin_nontemporal_store(v, &C[(size_t)r * NB + c]);
                es += __expf(v);
                ms += (labc[n] == labr) ? v : 0.f;
            }
#pragma unroll
            for (int off = 1; off < 16; off <<= 1) {
                es += __shfl_xor(es, off);
                ms += __shfl_xor(ms, off);
            }
            if (l15 == 0) {
                int o = rl * 4 + wc * 2;
                pl[o] = es; pl[o + 1] = ms;
            }
        }
    }
    __syncthreads();
    if (tid < 128) {
        float es = pl[tid * 4]     + pl[tid * 4 + 2];
        float ms = pl[tid * 4 + 1] + pl[tid * 4 + 3];
        pe[tn * NB + m0 + tid] = es;
        pm[tn * NB + m0 + tid] = ms;
    }
}

// ---------------------------------------------------------------------------
// Kernel 4: reduce 64 column-tile partials -> per-row loss.
// ---------------------------------------------------------------------------
__global__ __launch_bounds__(256) void loss_final(
    const float* __restrict__ pe, const float* __restrict__ pm,
    const int* __restrict__ labels, const int* __restrict__ hist,
    float* __restrict__ per_row)
{
    int row = blockIdx.x * 256 + threadIdx.x;
    float es = 0.f, ms = 0.f;
#pragma unroll
    for (int t = 0; t < 64; ++t) {
        es += pe[t * NB + row];
        ms += pm[t * NB + row];
    }
    per_row[row] = logf(es) - ms / (float)hist[labels[row]];
}

// ---------------------------------------------------------------------------
// Kernel 5: deterministic mean of per_row -> out[0]
// ---------------------------------------------------------------------------
__global__ __launch_bounds__(256) void finalize(
    const float* __restrict__ per_row, float* __restrict__ out)
{
    __shared__ float sm[256];
    float s = 0.f;
    for (int i = threadIdx.x; i < NB; i += 256) s += per_row[i];
    sm[threadIdx.x] = s;
    __syncthreads();
    for (int k = 128; k; k >>= 1) {
        if (threadIdx.x < k) sm[threadIdx.x] += sm[threadIdx.x + k];
        __syncthreads();
    }
    if (threadIdx.x == 0) out[0] = sm[0] * (1.0f / (float)NB);
}

extern "C" void kernel_launch(void* const* d_in, const int* in_sizes, int n_in,
                              void* d_out, int out_size, void* d_ws, size_t ws_size,
                              hipStream_t stream) {
    const int*   labels = (const int*)d_in[0];
    const float* A      = (const float*)d_in[1];
    const float* Bm     = (const float*)d_in[2];
    float* out = (float*)d_out;

    // workspace layout (~20.2 MB)
    char* ws = (char*)d_ws;
    unsigned char* wa = (unsigned char*)(ws);                   // 8 MB
    unsigned char* wb = (unsigned char*)(ws + 8388608);         // 8 MB
    float* na      = (float*)(ws + 16777216);                   // 32 KB
    float* nb      = (float*)(ws + 16809984);                   // 32 KB
    float* per_row = (float*)(ws + 16842752);                   // 32 KB
    int*   hist    = (int*)  (ws + 16875520);                   // 512 B
    float* pe      = (float*)(ws + 16908288);                   // 2 MB
    float* pm      = (float*)(ws + 19005440);                   // 2 MB

    float* cosm = out + 1;   // out[0]=loss, out[1..] = cos_score row-major

    prep_kernel<<<4096, 256, 0, stream>>>(A, Bm, wa, wb, na, nb);
    hist_kernel<<<1,    256, 0, stream>>>(labels, hist);
    gemm_cos   <<<4096, 256, 0, stream>>>(wa, wb, na, nb, labels, cosm, pe, pm);
    loss_final <<<32,   256, 0, stream>>>(pe, pm, labels, hist, per_row);
    finalize   <<<1,    256, 0, stream>>>(per_row, out);
}

// Round 7
// 243.460 us; speedup vs baseline: 4.8264x; 1.1455x over previous
//
#include <hip/hip_runtime.h>
#include <hip/hip_bf16.h>

#define NB 8192   // batch
#define ND 1024   // feature dim

typedef __bf16 bf16x8 __attribute__((ext_vector_type(8)));
typedef float  f32x4  __attribute__((ext_vector_type(4)));

// async global -> LDS, 16B per lane. LDS dest = wave-uniform base + lane*16.
__device__ inline void gload_lds16(const void* g, void* l) {
    __builtin_amdgcn_global_load_lds(
        (const __attribute__((address_space(1))) unsigned int*)g,
        (__attribute__((address_space(3))) unsigned int*)l,
        16, 0, 0);
}

__device__ inline unsigned short f2bf(float x) {
    unsigned int u = __float_as_uint(x);
    return (unsigned short)((u + 0x7fffu + ((u >> 16) & 1u)) >> 16);
}

#define BARRIER() asm volatile("s_barrier" ::: "memory")
#define VMCNT2()  asm volatile("s_waitcnt vmcnt(2)" ::: "memory")
#define VMCNT0()  asm volatile("s_waitcnt vmcnt(0)" ::: "memory")
#define LGKM0()   do { asm volatile("s_waitcnt lgkmcnt(0)" ::: "memory"); \
                       __builtin_amdgcn_sched_barrier(0); } while (0)

// ---------------------------------------------------------------------------
// Kernel 1: per-row L2 norms of A and B + bf16 conversion into workspace.
// ---------------------------------------------------------------------------
__global__ __launch_bounds__(256) void prep_kernel(
    const float* __restrict__ A, const float* __restrict__ Bm,
    unsigned short* __restrict__ wa, unsigned short* __restrict__ wb,
    float* __restrict__ na, float* __restrict__ nb)
{
    int b = blockIdx.x;
    int wid = threadIdx.x >> 6, lane = threadIdx.x & 63;
    const float* src; unsigned short* dst; float* nrm; int row;
    if (b < 2048) { src = A;  dst = wa; nrm = na; row = b * 4 + wid; }
    else          { src = Bm; dst = wb; nrm = nb; row = (b - 2048) * 4 + wid; }

    const float*    rp = src + (size_t)row * ND;
    unsigned short* wp = dst + (size_t)row * ND;

    float ss = 0.f;
#pragma unroll
    for (int t = 0; t < 4; ++t) {
        int c = lane * 4 + t * 256;
        float4 v = *reinterpret_cast<const float4*>(rp + c);
        ss += v.x * v.x + v.y * v.y + v.z * v.z + v.w * v.w;
        ushort4 u;
        u.x = f2bf(v.x); u.y = f2bf(v.y); u.z = f2bf(v.z); u.w = f2bf(v.w);
        *reinterpret_cast<ushort4*>(wp + c) = u;
    }
#pragma unroll
    for (int off = 32; off; off >>= 1) ss += __shfl_xor(ss, off);
    if (lane == 0) nrm[row] = sqrtf(ss);
}

// ---------------------------------------------------------------------------
// Kernel 2: label histogram (integer LDS atomics -> deterministic).
// ---------------------------------------------------------------------------
__global__ __launch_bounds__(256) void hist_kernel(
    const int* __restrict__ labels, int* __restrict__ hist)
{
    __shared__ int h[128];
    int tid = threadIdx.x;
    if (tid < 128) h[tid] = 0;
    __syncthreads();
    for (int i = tid; i < NB; i += 256) atomicAdd(&h[labels[i]], 1);
    __syncthreads();
    if (tid < 128) hist[tid] = h[tid];
}

// ---------------------------------------------------------------------------
// Kernel 3: 256x256-tile bf16 GEMM, BK=64, 2 K-tile LDS dbuf (128 KiB),
// 4 phases/K-tile (quadrants (ks,mh)), ONE half-tile staged per phase,
// DERIVED counted waits (never drain just-issued loads):
//   stage order during tile T: hB0,hB1,hA0,hA1 of T+1 at P1..P4.
//   G1 (end-P1) = vmcnt(2): completes hA1(T) [consumed at P2], leaves
//                 hB0(T+2) in flight.
//   G2 (end-P4) = vmcnt(2): completes B0,B1,A0 of T+1 [consumed at P1],
//                 leaves hA1(T+1) in flight.
// T2 granule swizzle on both sides (R4-verified addressing). setprio on MFMA.
// Epilogue: scale to cos, write C, fused per-row loss partials.
// ---------------------------------------------------------------------------
__global__ __launch_bounds__(512, 2) void gemm_cos(
    const unsigned short* __restrict__ wa, const unsigned short* __restrict__ wb,
    const float* __restrict__ na, const float* __restrict__ nb,
    const int* __restrict__ labels,
    float* __restrict__ C, float* __restrict__ pe, float* __restrict__ pm)
{
    // [buf 2][ A 256x64 | B 256x64 ] bf16 = 2 x 32768 shorts = 128 KiB
    __shared__ unsigned short lds[65536];

    const int bid = blockIdx.x;                 // 1024 blocks
    const int tm  = (bid & 7) * 4 + ((bid >> 3) & 3);
    const int tn  = bid >> 5;

    const int tid  = threadIdx.x;
    const int lane = tid & 63;
    const int wid  = tid >> 6;
    const int wr   = wid >> 2, wc = wid & 3;
    const int l15  = lane & 15, lg = lane >> 4;   // lg in 0..3

    const int m0 = tm * 256, n0 = tn * 256;

    // ---- staging: thread tid -> row tid>>3 (0..63), 16B granule tid&7;
    // global granule pre-swizzled: (tid&7) ^ (row&7).
    const int srow6 = tid >> 3;
    const int sgr   = (tid & 7) ^ (srow6 & 7);
    const unsigned short* pA0 = wa + (size_t)(m0 + srow6) * ND + sgr * 8;       // rows 0..63 (+128 in STG)
    const unsigned short* pA1 = pA0 + 64 * ND;                                  // rows 64..127 (+128)
    const unsigned short* pB0 = wb + (size_t)(n0 + srow6) * ND + sgr * 8;
    const unsigned short* pB1 = pB0 + 64 * ND;
    const int stW  = wid * 512;      // wave-uniform dest base per 64-row chunk
    const int ND128 = 128 * ND;

    // ---- fragment reads (R4-verified): row*64 + swz, XOR 32 shorts for ks=1.
    const int swz0  = ((((l15 >> 2) & 1) << 2) | (lg ^ (l15 & 3))) * 8;
    const int bA0 = (wr * 128 + l15) * 64 + swz0;
    const int bA1 = bA0 ^ 32;
    const int bB0 = 16384 + (wc * 64 + l15) * 64 + swz0;
    const int bB1 = bB0 ^ 32;

    f32x4 acc[8][4];
#pragma unroll
    for (int i = 0; i < 8; ++i)
#pragma unroll
        for (int j = 0; j < 4; ++j) acc[i][j] = (f32x4){0.f, 0.f, 0.f, 0.f};

    bf16x8 bq[4];

    // stage one half-tile: 64-row chunk -> DOFF, +128-row chunk -> DOFF+8192
#define STG(P, DOFF) do { \
    gload_lds16((P),          &lds[(DOFF) + stW]); \
    gload_lds16((P) + ND128,  &lds[(DOFF) + 8192 + stW]); } while (0)

#define PH(CB, BA, BB, MH, RB, STGX, GATE) { \
    if (RB) { _Pragma("unroll") \
        for (int n_ = 0; n_ < 4; ++n_) \
            bq[n_] = *reinterpret_cast<const bf16x8*>(&lds[(CB) + (BB) + n_ * 1024]); } \
    bf16x8 af[4]; \
    _Pragma("unroll") \
    for (int m_ = 0; m_ < 4; ++m_) \
        af[m_] = *reinterpret_cast<const bf16x8*>( \
            &lds[(CB) + (BA) + ((MH) * 4 + m_) * 1024]); \
    STGX; \
    BARRIER(); \
    LGKM0(); \
    __builtin_amdgcn_s_setprio(1); \
    _Pragma("unroll") \
    for (int m_ = 0; m_ < 4; ++m_) \
        _Pragma("unroll") \
        for (int n_ = 0; n_ < 4; ++n_) \
            acc[(MH) * 4 + m_][n_] = __builtin_amdgcn_mfma_f32_16x16x32_bf16( \
                af[m_], bq[n_], acc[(MH) * 4 + m_][n_], 0, 0, 0); \
    __builtin_amdgcn_s_setprio(0); \
    GATE; \
    BARRIER(); }

    // Prologue: stage all 4 halves of tile 0 into buf0; full drain (cold).
    STG(pA0, 0);  STG(pA1, 4096);
    STG(pB0, 16384); STG(pB1, 16384 + 4096);
    VMCNT0();
    BARRIER();

#pragma unroll
    for (int t = 0; t < 16; ++t) {
        const int cb = (t & 1) * 32768;       // consume buffer
        const int sb = cb ^ 32768;            // stage buffer (tile t+1)
        const int ko = (t + 1) * 64;          // global k-offset (shorts)
        if (t < 15) {
            // P1: q=(ks0,mh0); stage hB0(t+1); G1 = vmcnt(2) [hA1(t) done]
            PH(cb, bA0, bB0, 0, 1, STG(pB0 + ko, sb + 16384),        VMCNT2())
            // P2: q=(ks0,mh1); stage hB1(t+1)
            PH(cb, bA0, bB0, 1, 0, STG(pB1 + ko, sb + 16384 + 4096), (void)0)
            // P3: q=(ks1,mh0); stage hA0(t+1)
            PH(cb, bA1, bB1, 0, 1, STG(pA0 + ko, sb),                (void)0)
            // P4: q=(ks1,mh1); stage hA1(t+1); G2 = vmcnt(2) [B0,B1,A0 done]
            PH(cb, bA1, bB1, 1, 0, STG(pA1 + ko, sb + 4096),         VMCNT2())
        } else {
            // last tile: no staging; G1 must fully drain (only hA1(15) left)
            PH(cb, bA0, bB0, 0, 1, (void)0, VMCNT0())
            PH(cb, bA0, bB0, 1, 0, (void)0, (void)0)
            PH(cb, bA1, bB1, 0, 1, (void)0, (void)0)
            PH(cb, bA1, bB1, 1, 0, (void)0, (void)0)
        }
    }

#undef PH
#undef STG

    // ---------------- epilogue: cos write + fused loss partials ------------
    __syncthreads();                 // LDS buffers now reusable
    float* pl = reinterpret_cast<float*>(lds);   // [256 rows][4 wc][2] floats

    float nbv[4]; int labc[4];
#pragma unroll
    for (int n = 0; n < 4; ++n) {
        int c = n0 + wc * 64 + n * 16 + l15;
        nbv[n] = nb[c]; labc[n] = labels[c];
    }

#pragma unroll
    for (int m = 0; m < 8; ++m) {
#pragma unroll
        for (int jj = 0; jj < 4; ++jj) {
            int rl = wr * 128 + m * 16 + lg * 4 + jj;   // 0..255
            int r  = m0 + rl;
            float nav = na[r]; int labr = labels[r];
            float es = 0.f, ms = 0.f;
#pragma unroll
            for (int n = 0; n < 4; ++n) {
                int c = n0 + wc * 64 + n * 16 + l15;
                float v = acc[m][n][jj] / fmaxf(nav * nbv[n], 1e-8f);
                C[(size_t)r * NB + c] = v;
                es += __expf(v);
                ms += (labc[n] == labr) ? v : 0.f;
            }
#pragma unroll
            for (int off = 1; off < 16; off <<= 1) {
                es += __shfl_xor(es, off);
                ms += __shfl_xor(ms, off);
            }
            if (l15 == 0) {
                int o = (rl * 4 + wc) * 2;
                pl[o] = es; pl[o + 1] = ms;
            }
        }
    }
    __syncthreads();
    if (tid < 256) {
        float es = 0.f, ms = 0.f;
#pragma unroll
        for (int w = 0; w < 4; ++w) {
            es += pl[(tid * 4 + w) * 2];
            ms += pl[(tid * 4 + w) * 2 + 1];
        }
        int grow = m0 + tid;
        pe[tn * NB + grow] = es;
        pm[tn * NB + grow] = ms;
    }
}

// ---------------------------------------------------------------------------
// Kernel 4: reduce 32 column-tile partials -> per-row loss.
// ---------------------------------------------------------------------------
__global__ __launch_bounds__(256) void loss_final(
    const float* __restrict__ pe, const float* __restrict__ pm,
    const int* __restrict__ labels, const int* __restrict__ hist,
    float* __restrict__ per_row)
{
    int row = blockIdx.x * 256 + threadIdx.x;
    float es = 0.f, ms = 0.f;
#pragma unroll
    for (int t = 0; t < 32; ++t) {
        es += pe[t * NB + row];
        ms += pm[t * NB + row];
    }
    per_row[row] = logf(es) - ms / (float)hist[labels[row]];
}

// ---------------------------------------------------------------------------
// Kernel 5: deterministic mean of per_row -> out[0]
// ---------------------------------------------------------------------------
__global__ __launch_bounds__(256) void finalize(
    const float* __restrict__ per_row, float* __restrict__ out)
{
    __shared__ float sm[256];
    float s = 0.f;
    for (int i = threadIdx.x; i < NB; i += 256) s += per_row[i];
    sm[threadIdx.x] = s;
    __syncthreads();
    for (int k = 128; k; k >>= 1) {
        if (threadIdx.x < k) sm[threadIdx.x] += sm[threadIdx.x + k];
        __syncthreads();
    }
    if (threadIdx.x == 0) out[0] = sm[0] * (1.0f / (float)NB);
}

extern "C" void kernel_launch(void* const* d_in, const int* in_sizes, int n_in,
                              void* d_out, int out_size, void* d_ws, size_t ws_size,
                              hipStream_t stream) {
    const int*   labels = (const int*)d_in[0];
    const float* A      = (const float*)d_in[1];
    const float* Bm     = (const float*)d_in[2];
    float* out = (float*)d_out;

    // workspace layout (~36.2 MB)
    char* ws = (char*)d_ws;
    unsigned short* wa = (unsigned short*)(ws);                     // 16 MB
    unsigned short* wb = (unsigned short*)(ws + 16777216);          // 16 MB
    float* na      = (float*)(ws + 33554432);                       // 32 KB
    float* nb      = (float*)(ws + 33554432 + 32768);               // 32 KB
    float* per_row = (float*)(ws + 33554432 + 65536);               // 32 KB
    int*   hist    = (int*)  (ws + 33554432 + 98304);               // 512 B
    float* pe      = (float*)(ws + 33554432 + 131072);              // 1 MB
    float* pm      = (float*)(ws + 33554432 + 131072 + 1048576);    // 1 MB

    float* cosm = out + 1;   // out[0]=loss, out[1..] = cos_score row-major

    prep_kernel<<<4096, 256, 0, stream>>>(A, Bm, wa, wb, na, nb);
    hist_kernel<<<1,    256, 0, stream>>>(labels, hist);
    gemm_cos   <<<1024, 512, 0, stream>>>(wa, wb, na, nb, labels, cosm, pe, pm);
    loss_final <<<32,   256, 0, stream>>>(pe, pm, labels, hist, per_row);
    finalize   <<<1,    256, 0, stream>>>(per_row, out);
}